// Round 11
// baseline (2672.152 us; speedup 1.0000x reference)
//
#include <hip/hip_runtime.h>

// Problem constants (fixed by the reference):
//   B=4, NV=100000, F=200000, D=64
#define BB    4
#define NVV   100000
#define FFC   200000
#define DD    64
#define TOTV  400000              // B*NV
#define TOTF  800000              // B*F
#define TOTE  4800000             // 6 directed edges per face
#define NPART 128                 // dst-partitions
#define VPP   3125                // TOTV / NPART exactly
#define FPW   1536                // faces per WG in bucket phase
#define NWGA  ((TOTF + FPW - 1) / FPW)   // 521 WGs
#define ROUNDS (FPW / 256)        // 6 rounds of 256 faces
#define SUBV  512                 // vertices per fused sub-block
#define SUBS  7                   // ceil(VPP / SUBV): 6x512 + 53
#define SRCBITS 19
#define SRCMASK 0x7FFFF

__device__ __forceinline__ int part_of(int v) { return v / VPP; }

// ---------------------------------------------------------------------------
// Round-8 law: scattered per-lane global atomics/stores cap at ~23G ops/s.
// Round-10: gather fine (199us), but CSR build still ~300us (adj scatter +
// bucket int2 round trip). This version removes the CSR entirely:
//   faces -> (pcount/pscan) -> bucket[packed 4B, dst-partition-grouped]
//         -> fused kernel: LDS f32 accumulator per 512-vertex sub-range,
//            edge-filter + coalesced row reads + ds_add_f32, fused finalize.
// Zero scattered global stores anywhere.
// ---------------------------------------------------------------------------

// Pre-pass: edges per dst-partition. LDS histogram, NPART global atomics/WG.
__global__ __launch_bounds__(256) void ul_pcount(
    const int* __restrict__ faces, int* __restrict__ partCnt)
{
    __shared__ int h[NPART];
    int tid = threadIdx.x;
    if (tid < NPART) h[tid] = 0;
    __syncthreads();
    for (int t = blockIdx.x * blockDim.x + tid; t < TOTF; t += gridDim.x * blockDim.x) {
        int off = (t / FFC) * NVV;
        const int* fp = faces + (size_t)t * 3;
        int a = fp[0] + off, b = fp[1] + off, c = fp[2] + off;
        atomicAdd(&h[part_of(a)], 2);
        atomicAdd(&h[part_of(b)], 2);
        atomicAdd(&h[part_of(c)], 2);
    }
    __syncthreads();
    if (tid < NPART && h[tid]) atomicAdd(&partCnt[tid], h[tid]);
}

// Scan the partition counts -> pbase (exclusive starts) + pcur (cursors).
__global__ void ul_pscan(const int* __restrict__ partCnt,
                         int* __restrict__ pbase, int* __restrict__ pcur)
{
    __shared__ int s[NPART];
    int t = threadIdx.x;              // NPART threads
    int v = partCnt[t];
    s[t] = v;
    __syncthreads();
    for (int o = 1; o < NPART; o <<= 1) {
        int w = (t >= o) ? s[t - o] : 0;
        __syncthreads();
        s[t] += w;
        __syncthreads();
    }
    int ex = s[t] - v;
    pbase[t] = ex;
    pcur[t]  = ex;
}

// Bucket: 256 faces/round -> 1536 packed edges -> LDS hist/scan/reorder ->
// partition-grouped flush (runs of ~12 ints). Packed: (dst_local<<19)|src.
__global__ __launch_bounds__(256) void ul_bucket(
    const int* __restrict__ faces, int* __restrict__ pcur,
    unsigned int* __restrict__ bucket)
{
    __shared__ int      hist[NPART];
    __shared__ int      offs[NPART];
    __shared__ int      gbase[NPART];
    __shared__ unsigned ebuf[1536];
    __shared__ short    pidb[1536];
    int tid = threadIdx.x;
    int wg  = blockIdx.x;

    for (int r = 0; r < ROUNDS; ++r) {
        int f = wg * FPW + r * 256 + tid;
        bool valid = f < TOTF;
        int dsts[6], srcs[6], slot[6];
        if (valid) {
            int off = (f / FFC) * NVV;
            const int* fp = faces + (size_t)f * 3;
            int a = fp[0] + off, b = fp[1] + off, c = fp[2] + off;
            dsts[0] = a; srcs[0] = b;  dsts[1] = a; srcs[1] = c;
            dsts[2] = b; srcs[2] = a;  dsts[3] = b; srcs[3] = c;
            dsts[4] = c; srcs[4] = a;  dsts[5] = c; srcs[5] = b;
        }
        if (tid < NPART) hist[tid] = 0;
        __syncthreads();
        if (valid) {
            #pragma unroll
            for (int k = 0; k < 6; ++k)
                slot[k] = atomicAdd(&hist[part_of(dsts[k])], 1);
        }
        __syncthreads();
        if (tid < NPART) offs[tid] = hist[tid];
        __syncthreads();
        for (int o = 1; o < NPART; o <<= 1) {
            int w = 0;
            if (tid < NPART && tid >= o) w = offs[tid - o];
            __syncthreads();
            if (tid < NPART) offs[tid] += w;
            __syncthreads();
        }
        if (tid < NPART) {
            offs[tid] -= hist[tid];                       // inclusive -> exclusive
            gbase[tid] = atomicAdd(&pcur[tid], hist[tid]); // reserve global space
        }
        __syncthreads();
        int roundEdges = offs[NPART - 1] + hist[NPART - 1];
        if (valid) {
            #pragma unroll
            for (int k = 0; k < 6; ++k) {
                int p   = part_of(dsts[k]);
                int dl  = dsts[k] - p * VPP;
                int pos = offs[p] + slot[k];
                ebuf[pos] = ((unsigned)dl << SRCBITS) | (unsigned)srcs[k];
                pidb[pos] = (short)p;
            }
        }
        __syncthreads();
        for (int e = tid; e < roundEdges; e += 256) {
            int q = pidb[e];
            bucket[gbase[q] + (e - offs[q])] = ebuf[e];
        }
        __syncthreads();   // protect LDS reuse next round
    }
}

// Fused accumulate + finalize. One WG per (partition, 512-vertex sub-range).
// LDS f32 accumulator; edges filtered by ballot; per hit edge one coalesced
// 256B row read + ds_add_f32 row accumulate (8-deep MLP); coalesced epilogue.
__global__ __launch_bounds__(512) void ul_fuse(
    const float* __restrict__ v, const unsigned int* __restrict__ bucket,
    const int* __restrict__ pbase, const int* __restrict__ partCnt,
    float* __restrict__ out)
{
    __shared__ float acc[SUBV * DD];   // 128 KB
    __shared__ int   ldeg[SUBV];       // 2 KB
    int p        = blockIdx.x / SUBS;
    int s        = blockIdx.x % SUBS;
    int sub_base = s * SUBV;                    // local vertex base in partition
    int nv       = min(SUBV, VPP - sub_base);   // 512 or 53
    int tid  = threadIdx.x;
    int lane = tid & 63;
    int wv   = tid >> 6;                        // 8 waves

    for (int i = tid; i < SUBV; i += 512) ldeg[i] = 0;
    for (int i = tid; i < SUBV * DD; i += 512) acc[i] = 0.0f;
    __syncthreads();

    int ebase = pbase[p], ecnt = partCnt[p];
    for (int c = 0; c < ecnt; c += 512) {
        int e = c + wv * 64 + lane;
        unsigned pk = (e < ecnt) ? bucket[ebase + e] : 0xFFFFFFFFu;
        int src = (int)(pk & SRCMASK);
        int dl  = (int)(pk >> SRCBITS) - sub_base;   // sentinel -> 8191-sub_base >= nv
        bool hit = (unsigned)dl < (unsigned)nv;
        if (hit) atomicAdd(&ldeg[dl], 1);
        unsigned long long mb = __ballot(hit);
        while (mb) {
            int   idx[8];
            int   dls[8];
            float rows[8];
            #pragma unroll
            for (int k = 0; k < 8; ++k) {
                if (mb) { idx[k] = __ffsll(mb) - 1; mb &= mb - 1; }
                else      idx[k] = -1;
            }
            #pragma unroll
            for (int k = 0; k < 8; ++k) {
                if (idx[k] >= 0) {
                    int sj = __shfl(src, idx[k]);
                    dls[k] = __shfl(dl,  idx[k]);
                    rows[k] = v[(size_t)sj * DD + lane];
                }
            }
            #pragma unroll
            for (int k = 0; k < 8; ++k) {
                if (idx[k] >= 0)
                    atomicAdd(&acc[dls[k] * DD + lane], rows[k]);
            }
        }
    }
    __syncthreads();

    // epilogue: out = (deg*v - acc)/(deg+eps), coalesced, wave per row
    for (int r = wv; r < nv; r += 8) {
        int vg = p * VPP + sub_base + r;
        float dg = (float)ldeg[r];
        float vi = v[(size_t)vg * DD + lane];
        out[(size_t)vg * DD + lane] = (dg * vi - acc[r * DD + lane]) / (dg + 1e-12f);
    }
}

// ---------------------------------------------------------------------------
// Fallback path (round-2 atomic scatter) in case ws_size is tiny.
// ---------------------------------------------------------------------------
__global__ __launch_bounds__(256) void ul_scatter(
    const float* __restrict__ v, const int* __restrict__ faces,
    float* __restrict__ nbr, float* __restrict__ deg)
{
    int gid  = blockIdx.x * blockDim.x + threadIdx.x;
    int wid  = gid >> 6;
    int lane = gid & 63;
    if (wid >= TOTF) return;
    int off = (wid / FFC) * NVV;
    const int* fp = faces + (size_t)wid * 3;
    int ia = fp[0] + off, ib = fp[1] + off, ic = fp[2] + off;
    float va = v[(size_t)ia * DD + lane];
    float vb = v[(size_t)ib * DD + lane];
    float vc = v[(size_t)ic * DD + lane];
    atomicAdd(&nbr[(size_t)ia * DD + lane], vb + vc);
    atomicAdd(&nbr[(size_t)ib * DD + lane], va + vc);
    atomicAdd(&nbr[(size_t)ic * DD + lane], va + vb);
    if (lane < 3) {
        int t = (lane == 0) ? ia : ((lane == 1) ? ib : ic);
        atomicAdd(&deg[t], 2.0f);
    }
}

__global__ __launch_bounds__(256) void ul_finalize(
    const float4* __restrict__ v4, const float* __restrict__ deg,
    float4* __restrict__ out4, int n4)
{
    int i = blockIdx.x * blockDim.x + threadIdx.x;
    if (i >= n4) return;
    float d = deg[i >> 4];
    float4 vv = v4[i];
    float4 nb = out4[i];
    float inv = 1.0f / (d + 1e-12f);
    float4 r;
    r.x = (d * vv.x - nb.x) * inv;
    r.y = (d * vv.y - nb.y) * inv;
    r.z = (d * vv.z - nb.z) * inv;
    r.w = (d * vv.w - nb.w) * inv;
    out4[i] = r;
}

// ---------------------------------------------------------------------------

extern "C" void kernel_launch(void* const* d_in, const int* in_sizes, int n_in,
                              void* d_out, int out_size, void* d_ws, size_t ws_size,
                              hipStream_t stream)
{
    const float* verts = (const float*)d_in[0];
    const int*   faces = (const int*)d_in[1];
    float*       out   = (float*)d_out;

    // Workspace layout (256B-aligned): partCnt[NPART] pbase[NPART] pcur[NPART]
    //                                  bucket[TOTE] (packed 4B edges, 19.2 MB)
    size_t o_pcnt   = 0;
    size_t o_pbase  = o_pcnt  + ((size_t)NPART * 4 + 255) / 256 * 256;
    size_t o_pcur   = o_pbase + ((size_t)NPART * 4 + 255) / 256 * 256;
    size_t o_bucket = o_pcur  + ((size_t)NPART * 4 + 255) / 256 * 256;
    size_t needed   = o_bucket + (size_t)TOTE * 4;

    if (ws_size >= needed) {
        int*          partCnt = (int*)((char*)d_ws + o_pcnt);
        int*          pbase   = (int*)((char*)d_ws + o_pbase);
        int*          pcur    = (int*)((char*)d_ws + o_pcur);
        unsigned int* bucket  = (unsigned int*)((char*)d_ws + o_bucket);

        hipMemsetAsync(partCnt, 0, NPART * 4, stream);

        ul_pcount<<<512, 256, 0, stream>>>(faces, partCnt);
        ul_pscan <<<1, NPART, 0, stream>>>(partCnt, pbase, pcur);
        ul_bucket<<<NWGA, 256, 0, stream>>>(faces, pcur, bucket);
        ul_fuse  <<<NPART * SUBS, 512, 0, stream>>>(verts, bucket, pbase, partCnt, out);
    } else {
        // Fallback: float-atomic scatter (round-2 path).
        float* deg = (float*)d_ws;
        hipMemsetAsync(d_out, 0, (size_t)out_size * sizeof(float), stream);
        hipMemsetAsync(deg,   0, (size_t)TOTV * sizeof(float), stream);
        long long thr = (long long)TOTF * 64;
        ul_scatter<<<(int)((thr + 255) / 256), 256, 0, stream>>>(verts, faces, out, deg);
        int n4 = out_size / 4;
        ul_finalize<<<(n4 + 255) / 256, 256, 0, stream>>>(
            (const float4*)verts, deg, (float4*)out, n4);
    }
}